// Round 2
// baseline (121.768 us; speedup 1.0000x reference)
//
#include <hip/hip_runtime.h>

// TensorTrainEmbedding, bucketed-gather version.
// Per element b: v0 = end_core[h2] (4x16), core = cores[h1] (4x16x16),
//                start = start_core[h0] (4x16)
//   t[d][s][e] = sum_r core[d][s][r]*v0[e][r]
//   out[b][d'*16+d*4+e] = sum_s start[d'][s]*t[d][s][e]
//
// h1 draws are 36.8% duplicates (B == HRANGE == 131072); unbucketed, duplicate
// 4 KiB core fetches miss L3 (512 MiB table vs 256 MiB L3). Bucketing by
// h1>>5 (4096 buckets, ~32 elems each) makes same-h1 touches temporally
// adjacent -> duplicate fetches hit L2/L3, saving ~180 MB HBM per dispatch.

#define WPB 4           // waves per block in main kernel
#define T_STRIDE 20     // LDS stride for t: <=2-way bank alias (free per m136)
#define NBINS 4096
#define BIN_SHIFT 5     // bucket = h1 >> 5

// ws layout
#define WS_HIST_OFF 0                        // NBINS u32 = 16 KiB
#define WS_OFFS_OFF (NBINS * 4)              // NBINS u32 = 16 KiB
#define WS_PERM_OFF (2 * NBINS * 4)          // B u32 = 512 KiB
#define WS_NEEDED   (2 * NBINS * 4 + 131072 * 4)

__global__ __launch_bounds__(256) void hist_kernel(
    const int* __restrict__ hs, unsigned* __restrict__ hist, int B)
{
    int b = blockIdx.x * 256 + threadIdx.x;
    if (b < B) {
        unsigned h1 = (unsigned)hs[3 * b + 1];
        atomicAdd(&hist[h1 >> BIN_SHIFT], 1u);
    }
}

// 1 block, 256 threads; exclusive prefix over NBINS (16 bins/thread)
__global__ __launch_bounds__(256) void scan_kernel(
    const unsigned* __restrict__ hist, unsigned* __restrict__ offs)
{
    __shared__ unsigned sums[256];
    const int t = threadIdx.x;
    unsigned local[16];
    unsigned s = 0;
    #pragma unroll
    for (int i = 0; i < 16; ++i) { local[i] = hist[t * 16 + i]; s += local[i]; }
    sums[t] = s;
    __syncthreads();
    // Hillis-Steele inclusive scan over 256 partials
    #pragma unroll
    for (int st = 1; st < 256; st <<= 1) {
        unsigned v = (t >= st) ? sums[t - st] : 0u;
        __syncthreads();
        sums[t] += v;
        __syncthreads();
    }
    unsigned run = sums[t] - s;   // exclusive prefix of this thread's chunk
    #pragma unroll
    for (int i = 0; i < 16; ++i) { offs[t * 16 + i] = run; run += local[i]; }
}

__global__ __launch_bounds__(256) void scatter_kernel(
    const int* __restrict__ hs, unsigned* __restrict__ offs,
    unsigned* __restrict__ perm, int B)
{
    int b = blockIdx.x * 256 + threadIdx.x;
    if (b < B) {
        unsigned h1 = (unsigned)hs[3 * b + 1];
        unsigned pos = atomicAdd(&offs[h1 >> BIN_SHIFT], 1u);
        perm[pos] = (unsigned)b;
    }
}

__global__ __launch_bounds__(256) void tt_embed_kernel(
    const int* __restrict__ hs,
    const float* __restrict__ start_core,
    const float* __restrict__ end_core,
    const float* __restrict__ cores,
    const unsigned* __restrict__ perm,   // may be null -> identity
    float* __restrict__ out,
    int B)
{
    __shared__ __align__(16) float lds_t[WPB][16 * T_STRIDE];

    const int tid  = threadIdx.x;
    const int wave = tid >> 6;
    const int lane = tid & 63;

    int i = blockIdx.x * WPB + wave;
    const bool active = (i < B);
    int b = i;
    if (active && perm) b = (int)perm[i];
    b = __builtin_amdgcn_readfirstlane(b);   // wave-uniform -> scalar path

    float st[16];
    float t[4];

    if (active) {
        const int h0 = __builtin_amdgcn_readfirstlane(hs[3 * b + 0]);
        const int h1 = __builtin_amdgcn_readfirstlane(hs[3 * b + 1]);
        const int h2 = __builtin_amdgcn_readfirstlane(hs[3 * b + 2]);

        // phase 1: lane = (d = lane>>4, s = lane&15) owns one 64 B core row
        const float* crp = cores + ((size_t)h1 << 10) + lane * 16;
        float c[16];
        *(float4*)(c + 0)  = *(const float4*)(crp + 0);
        *(float4*)(c + 4)  = *(const float4*)(crp + 4);
        *(float4*)(c + 8)  = *(const float4*)(crp + 8);
        *(float4*)(c + 12) = *(const float4*)(crp + 12);

        const float* stp = start_core + ((size_t)h0 << 6) + ((lane >> 4) << 4);
        *(float4*)(st + 0)  = *(const float4*)(stp + 0);
        *(float4*)(st + 4)  = *(const float4*)(stp + 4);
        *(float4*)(st + 8)  = *(const float4*)(stp + 8);
        *(float4*)(st + 12) = *(const float4*)(stp + 12);

        // v0 = end_core[h2]: wave-uniform -> SGPR broadcast
        const float* v0p = end_core + ((size_t)h2 << 6);
        #pragma unroll
        for (int e = 0; e < 4; ++e) {
            const float* ve = v0p + e * 16;
            float a = c[0] * ve[0];
            #pragma unroll
            for (int r = 1; r < 16; ++r)
                a = fmaf(c[r], ve[r], a);
            t[e] = a;
        }

        const int d = lane >> 4;
        const int s = lane & 15;
        #pragma unroll
        for (int e = 0; e < 4; ++e)
            lds_t[wave][(d * 4 + e) * T_STRIDE + s] = t[e];
    }

    __syncthreads();

    if (active) {
        // phase 2: lane = output index o = d'*16 + (d*4+e)
        const float* tp = &lds_t[wave][(lane & 15) * T_STRIDE];
        float tt[16];
        *(float4*)(tt + 0)  = *(const float4*)(tp + 0);
        *(float4*)(tt + 4)  = *(const float4*)(tp + 4);
        *(float4*)(tt + 8)  = *(const float4*)(tp + 8);
        *(float4*)(tt + 12) = *(const float4*)(tp + 12);

        float a = st[0] * tt[0];
        #pragma unroll
        for (int k = 1; k < 16; ++k)
            a = fmaf(st[k], tt[k], a);

        out[((size_t)b << 6) + lane] = a;   // 256 B contiguous per wave
    }
}

extern "C" void kernel_launch(void* const* d_in, const int* in_sizes, int n_in,
                              void* d_out, int out_size, void* d_ws, size_t ws_size,
                              hipStream_t stream) {
    const int*   hs         = (const int*)d_in[0];
    const float* start_core = (const float*)d_in[1];
    const float* end_core   = (const float*)d_in[2];
    const float* cores      = (const float*)d_in[3];
    float* out = (float*)d_out;

    const int B = in_sizes[0] / 3;                 // hs is (B, 3)
    const int grid_main = (B + WPB - 1) / WPB;
    const int grid_b    = (B + 255) / 256;

    const bool use_sort = (ws_size >= (size_t)WS_NEEDED) && (B == 131072);

    if (use_sort) {
        unsigned* hist = (unsigned*)((char*)d_ws + WS_HIST_OFF);
        unsigned* offs = (unsigned*)((char*)d_ws + WS_OFFS_OFF);
        unsigned* perm = (unsigned*)((char*)d_ws + WS_PERM_OFF);

        hipMemsetAsync(hist, 0, NBINS * 4, stream);
        hipLaunchKernelGGL(hist_kernel, dim3(grid_b), dim3(256), 0, stream,
                           hs, hist, B);
        hipLaunchKernelGGL(scan_kernel, dim3(1), dim3(256), 0, stream,
                           hist, offs);
        hipLaunchKernelGGL(scatter_kernel, dim3(grid_b), dim3(256), 0, stream,
                           hs, offs, perm, B);
        hipLaunchKernelGGL(tt_embed_kernel, dim3(grid_main), dim3(256), 0, stream,
                           hs, start_core, end_core, cores, perm, out, B);
    } else {
        hipLaunchKernelGGL(tt_embed_kernel, dim3(grid_main), dim3(256), 0, stream,
                           hs, start_core, end_core, cores, (const unsigned*)nullptr,
                           out, B);
    }
}

// Round 3
// 108.679 us; speedup vs baseline: 1.1204x; 1.1204x over previous
//
#include <hip/hip_runtime.h>

// TensorTrainEmbedding, exact-dedup version.
// out[b] = start_core[h0] . (cores[h1] . end_core[h2]); core slice = 4 KiB.
// B == HRANGE == 131072 -> ~36.8% of h1 draws are duplicates. R2 showed
// cache-based dedup fails (concurrent cross-XCD misses don't merge), so this
// version dedups STRUCTURALLY: inverted index h1 -> {b}, one wave per
// distinct h1, core fetched exactly once, applied to every element in the bin.
//
// Per-b arithmetic is identical regardless of bin slot order -> deterministic.

#define CAP 16          // max elements per h1 bin (Poisson(1): P(>16) ~ 1e-10)
#define WPB 4           // waves per block
#define T_STRIDE 20     // LDS stride for t: <=2-way bank alias (free, m136)
#define HRANGE_C 131072

// ws layout: counts (512 KB) | table (8 MB)
#define WS_COUNTS_OFF 0
#define WS_TABLE_OFF  (HRANGE_C * 4)
#define WS_NEEDED     (HRANGE_C * 4 + HRANGE_C * CAP * 4)

// intra-wave LDS write->read fence (no s_barrier needed within a wave;
// sched_barrier required after inline lgkmcnt per guide rule 18)
#define WAVE_LDS_FENCE() do { \
    asm volatile("s_waitcnt lgkmcnt(0)" ::: "memory"); \
    __builtin_amdgcn_sched_barrier(0); \
} while (0)

__global__ __launch_bounds__(256) void build_kernel(
    const int* __restrict__ hs, unsigned* __restrict__ counts,
    unsigned* __restrict__ table, int B)
{
    int b = blockIdx.x * 256 + threadIdx.x;
    if (b < B) {
        unsigned h1 = (unsigned)hs[3 * b + 1];
        unsigned slot = atomicAdd(&counts[h1], 1u);
        if (slot < CAP) table[h1 * CAP + slot] = (unsigned)b;
    }
}

__global__ __launch_bounds__(256) void tt_embed_dedup_kernel(
    const int* __restrict__ hs,
    const float* __restrict__ start_core,
    const float* __restrict__ end_core,
    const float* __restrict__ cores,
    const unsigned* __restrict__ counts,
    const unsigned* __restrict__ table,
    float* __restrict__ out)
{
    __shared__ __align__(16) float lds_t[WPB][16 * T_STRIDE];

    const int tid  = threadIdx.x;
    const int wave = tid >> 6;
    const int lane = tid & 63;

    int bin = blockIdx.x * WPB + wave;
    bin = __builtin_amdgcn_readfirstlane(bin);

    int cnt = (int)counts[bin];              // wave-uniform -> s_load
    cnt = __builtin_amdgcn_readfirstlane(cnt);
    if (cnt == 0) return;                    // no barrier in kernel -> safe
    if (cnt > CAP) cnt = CAP;

    // load the 4 KiB core slice ONCE: lane = (d = lane>>4, s = lane&15)
    const float* crp = cores + ((size_t)bin << 10) + lane * 16;
    float c[16];
    *(float4*)(c + 0)  = *(const float4*)(crp + 0);
    *(float4*)(c + 4)  = *(const float4*)(crp + 4);
    *(float4*)(c + 8)  = *(const float4*)(crp + 8);
    *(float4*)(c + 12) = *(const float4*)(crp + 12);

    const int d = lane >> 4;
    const int s = lane & 15;
    float* tw = &lds_t[wave][(d * 4) * T_STRIDE + s];
    const float* tr = &lds_t[wave][(lane & 15) * T_STRIDE];

    for (int j = 0; j < cnt; ++j) {
        int b = (int)table[bin * CAP + j];
        b = __builtin_amdgcn_readfirstlane(b);
        const int h0 = __builtin_amdgcn_readfirstlane(hs[3 * b + 0]);
        const int h2 = __builtin_amdgcn_readfirstlane(hs[3 * b + 2]);

        // start row for phase 2: d' = lane>>4 (same per-lane layout as phase 1 d)
        const float* stp = start_core + ((size_t)h0 << 6) + ((lane >> 4) << 4);
        float st[16];
        *(float4*)(st + 0)  = *(const float4*)(stp + 0);
        *(float4*)(st + 4)  = *(const float4*)(stp + 4);
        *(float4*)(st + 8)  = *(const float4*)(stp + 8);
        *(float4*)(st + 12) = *(const float4*)(stp + 12);

        // v0 = end_core[h2]: wave-uniform -> SGPR broadcast
        const float* v0p = end_core + ((size_t)h2 << 6);
        #pragma unroll
        for (int e = 0; e < 4; ++e) {
            const float* ve = v0p + e * 16;
            float a = c[0] * ve[0];
            #pragma unroll
            for (int r = 1; r < 16; ++r)
                a = fmaf(c[r], ve[r], a);
            tw[e * T_STRIDE] = a;            // t[(d*4+e)*20 + s]
        }

        WAVE_LDS_FENCE();                    // intra-wave write->read ordering

        float tt[16];
        *(float4*)(tt + 0)  = *(const float4*)(tr + 0);
        *(float4*)(tt + 4)  = *(const float4*)(tr + 4);
        *(float4*)(tt + 8)  = *(const float4*)(tr + 8);
        *(float4*)(tt + 12) = *(const float4*)(tr + 12);

        float a = st[0] * tt[0];
        #pragma unroll
        for (int k = 1; k < 16; ++k)
            a = fmaf(st[k], tt[k], a);

        out[((size_t)b << 6) + lane] = a;    // 256 B contiguous per wave

        WAVE_LDS_FENCE();                    // WAR: next iter's writes vs reads
    }
}

// fallback (identity order, no ws) — R1 kernel
__global__ __launch_bounds__(256) void tt_embed_plain_kernel(
    const int* __restrict__ hs,
    const float* __restrict__ start_core,
    const float* __restrict__ end_core,
    const float* __restrict__ cores,
    float* __restrict__ out,
    int B)
{
    __shared__ __align__(16) float lds_t[WPB][16 * T_STRIDE];
    const int tid  = threadIdx.x;
    const int wave = tid >> 6;
    const int lane = tid & 63;

    int b = blockIdx.x * WPB + wave;
    b = __builtin_amdgcn_readfirstlane(b);
    if (b >= B) return;

    const int h0 = __builtin_amdgcn_readfirstlane(hs[3 * b + 0]);
    const int h1 = __builtin_amdgcn_readfirstlane(hs[3 * b + 1]);
    const int h2 = __builtin_amdgcn_readfirstlane(hs[3 * b + 2]);

    const float* crp = cores + ((size_t)h1 << 10) + lane * 16;
    float c[16];
    *(float4*)(c + 0)  = *(const float4*)(crp + 0);
    *(float4*)(c + 4)  = *(const float4*)(crp + 4);
    *(float4*)(c + 8)  = *(const float4*)(crp + 8);
    *(float4*)(c + 12) = *(const float4*)(crp + 12);

    const float* stp = start_core + ((size_t)h0 << 6) + ((lane >> 4) << 4);
    float st[16];
    *(float4*)(st + 0)  = *(const float4*)(stp + 0);
    *(float4*)(st + 4)  = *(const float4*)(stp + 4);
    *(float4*)(st + 8)  = *(const float4*)(stp + 8);
    *(float4*)(st + 12) = *(const float4*)(stp + 12);

    const float* v0p = end_core + ((size_t)h2 << 6);
    const int d = lane >> 4;
    const int s = lane & 15;
    #pragma unroll
    for (int e = 0; e < 4; ++e) {
        const float* ve = v0p + e * 16;
        float a = c[0] * ve[0];
        #pragma unroll
        for (int r = 1; r < 16; ++r)
            a = fmaf(c[r], ve[r], a);
        lds_t[wave][(d * 4 + e) * T_STRIDE + s] = a;
    }

    WAVE_LDS_FENCE();

    const float* tp = &lds_t[wave][(lane & 15) * T_STRIDE];
    float tt[16];
    *(float4*)(tt + 0)  = *(const float4*)(tp + 0);
    *(float4*)(tt + 4)  = *(const float4*)(tp + 4);
    *(float4*)(tt + 8)  = *(const float4*)(tp + 8);
    *(float4*)(tt + 12) = *(const float4*)(tp + 12);

    float a = st[0] * tt[0];
    #pragma unroll
    for (int k = 1; k < 16; ++k)
        a = fmaf(st[k], tt[k], a);
    out[((size_t)b << 6) + lane] = a;
}

extern "C" void kernel_launch(void* const* d_in, const int* in_sizes, int n_in,
                              void* d_out, int out_size, void* d_ws, size_t ws_size,
                              hipStream_t stream) {
    const int*   hs         = (const int*)d_in[0];
    const float* start_core = (const float*)d_in[1];
    const float* end_core   = (const float*)d_in[2];
    const float* cores      = (const float*)d_in[3];
    float* out = (float*)d_out;

    const int B = in_sizes[0] / 3;   // hs is (B, 3)

    const bool dedup = (B == HRANGE_C) && (ws_size >= (size_t)WS_NEEDED);

    if (dedup) {
        unsigned* counts = (unsigned*)((char*)d_ws + WS_COUNTS_OFF);
        unsigned* table  = (unsigned*)((char*)d_ws + WS_TABLE_OFF);

        hipMemsetAsync(counts, 0, HRANGE_C * 4, stream);
        hipLaunchKernelGGL(build_kernel, dim3((B + 255) / 256), dim3(256), 0,
                           stream, hs, counts, table, B);
        hipLaunchKernelGGL(tt_embed_dedup_kernel,
                           dim3(HRANGE_C / WPB), dim3(256), 0, stream,
                           hs, start_core, end_core, cores, counts, table, out);
    } else {
        hipLaunchKernelGGL(tt_embed_plain_kernel,
                           dim3((B + WPB - 1) / WPB), dim3(256), 0, stream,
                           hs, start_core, end_core, cores, out, B);
    }
}